// Round 4
// baseline (202.046 us; speedup 1.0000x reference)
//
#include <hip/hip_runtime.h>
#include <math.h>

#define D 768
#define NQKV 2304  // 3*D
#define NH 8
#define HD 96
#define NW 16
#define OVL 32
#define NLINES 8192
#define NCOMB 8256
#define MPAD 8320  // 65 * 128, zero-padded rows for guard-free GEMM
#define CH 64      // attention lines per block

typedef __bf16 bf16x8 __attribute__((ext_vector_type(8)));
typedef float f32x4 __attribute__((ext_vector_type(4)));

__device__ __forceinline__ unsigned short f2bf(float f) {
    unsigned int u = __float_as_uint(f);
    u += 0x7FFF + ((u >> 16) & 1);  // RNE
    return (unsigned short)(u >> 16);
}
__device__ __forceinline__ float bflo(unsigned int u) { return __uint_as_float(u << 16); }
__device__ __forceinline__ float bfhi(unsigned int u) { return __uint_as_float(u & 0xFFFF0000u); }

__device__ __forceinline__ void stage16(const unsigned short* g, unsigned short* l) {
    __builtin_amdgcn_global_load_lds(
        (const __attribute__((address_space(1))) unsigned int*)g,
        (__attribute__((address_space(3))) unsigned int*)l, 16, 0, 0);
}

// ---- fp32 -> bf16 converts -------------------------------------------------

__global__ __launch_bounds__(256) void convert_comb(const float* __restrict__ main_,
                                                    const float* __restrict__ begin_,
                                                    const float* __restrict__ end_,
                                                    unsigned short* __restrict__ dst) {
    const int i = blockIdx.x * 256 + threadIdx.x;  // MPAD*192 float4 groups
    const int row = i / 192;
    const int c = (i % 192) * 4;
    float4 v = make_float4(0.f, 0.f, 0.f, 0.f);
    if (row < NCOMB) {
        const float* src = (row < OVL) ? begin_ + (size_t)row * D
                         : (row < OVL + NLINES) ? main_ + (size_t)(row - OVL) * D
                                                : end_ + (size_t)(row - OVL - NLINES) * D;
        v = *(const float4*)(src + c);
    }
    ushort4 o;
    o.x = f2bf(v.x); o.y = f2bf(v.y); o.z = f2bf(v.z); o.w = f2bf(v.w);
    *(ushort4*)(dst + (size_t)row * D + c) = o;
}

// Converts in_proj_w (prescaling the Wq block by 96^-0.5), out_proj_w, and
// preps the scaled in-proj bias. w_dst = [in_w (3DD, wq scaled); out_w (DD)].
#define SCALE_Q 0.1020620726159657f
__global__ __launch_bounds__(256) void convert_w(const float* __restrict__ in_w,
                                                 const float* __restrict__ in_b,
                                                 const float* __restrict__ out_w,
                                                 unsigned short* __restrict__ w_dst,
                                                 float* __restrict__ bias_s) {
    const int i = (blockIdx.x * 256 + threadIdx.x) * 4;  // over 4*D*D floats
    const bool is_out = i >= 3 * D * D;
    const float4 v = is_out ? *(const float4*)(out_w + (i - 3 * D * D))
                            : *(const float4*)(in_w + i);
    const float s = (i < D * D) ? SCALE_Q : 1.0f;  // first DD floats = Wq rows
    ushort4 o;
    o.x = f2bf(v.x * s); o.y = f2bf(v.y * s); o.z = f2bf(v.z * s); o.w = f2bf(v.w * s);
    *(ushort4*)(w_dst + i) = o;
    if (blockIdx.x == 0) {  // 256 threads x 4 floats cover 1024 >= ... loop to 2304
        for (int b = threadIdx.x; b < NQKV; b += 256)
            bias_s[b] = in_b[b] * (b < D ? SCALE_Q : 1.0f);
    }
}

// ---- 128x128 MFMA GEMM tile, dual-plane BK=64: C = A @ B^T + bias ----------
template <bool BF16OUT>
__device__ __forceinline__ void gemm_tile(const unsigned short* __restrict__ A,
                                          const unsigned short* __restrict__ B,
                                          const float* __restrict__ bias,
                                          void* __restrict__ Cout, int ldc, int col_off,
                                          int m0, int n0) {
    __shared__ __align__(16) unsigned short As[2][128 * 32];
    __shared__ __align__(16) unsigned short Bs[2][128 * 32];
    const int tid = threadIdx.x;
    const int lane = tid & 63;
    const int wave = tid >> 6;
    const int wm = (wave & 1) * 64;
    const int wn = (wave >> 1) * 64;
    const int q = lane >> 4;
    const int l15 = lane & 15;

    const int srow = tid >> 2;       // 0..63
    const int scol = (tid & 3) * 8;  // k-granule within 32-k plane

    f32x4 acc[4][4] = {};

    for (int k0 = 0; k0 < D; k0 += 64) {
#pragma unroll
        for (int p = 0; p < 2; p++) {
            const int kp = k0 + p * 32 + scol;
            stage16(A + (size_t)(m0 + srow) * D + kp, As[p] + tid * 8);
            stage16(A + (size_t)(m0 + 64 + srow) * D + kp, As[p] + 2048 + tid * 8);
            stage16(B + (size_t)(n0 + srow) * D + kp, Bs[p] + tid * 8);
            stage16(B + (size_t)(n0 + 64 + srow) * D + kp, Bs[p] + 2048 + tid * 8);
        }
        __syncthreads();
#pragma unroll
        for (int p = 0; p < 2; p++) {
            bf16x8 af[4], bfr[4];
#pragma unroll
            for (int i = 0; i < 4; i++)
                af[i] = *(const bf16x8*)(As[p] + (wm + i * 16 + l15) * 32 + q * 8);
#pragma unroll
            for (int j = 0; j < 4; j++)
                bfr[j] = *(const bf16x8*)(Bs[p] + (wn + j * 16 + l15) * 32 + q * 8);
#pragma unroll
            for (int i = 0; i < 4; i++)
#pragma unroll
                for (int j = 0; j < 4; j++)
                    acc[i][j] =
                        __builtin_amdgcn_mfma_f32_16x16x32_bf16(af[i], bfr[j], acc[i][j], 0, 0, 0);
        }
        __syncthreads();
    }

#pragma unroll
    for (int i = 0; i < 4; i++) {
#pragma unroll
        for (int j = 0; j < 4; j++) {
#pragma unroll
            for (int r = 0; r < 4; r++) {
                const int row = m0 + wm + i * 16 + q * 4 + r;
                const int col = n0 + wn + j * 16 + l15;
                const float v = acc[i][j][r] + bias[col];
                if (BF16OUT)
                    ((unsigned short*)Cout)[(size_t)row * ldc + col_off + col] = f2bf(v);
                else
                    ((float*)Cout)[(size_t)row * ldc + col_off + col] = v;
            }
        }
    }
}

// Merged QKV: QKV[MPAD x 2304] = comb @ Wall^T + bias_s (Wq/bq pre-scaled)
__global__ __launch_bounds__(256) void qkv_gemm(const unsigned short* __restrict__ comb,
                                                const unsigned short* __restrict__ w_bf,
                                                const float* __restrict__ bias_s,
                                                unsigned short* __restrict__ QKV) {
    gemm_tile<true>(comb, w_bf, bias_s, QKV, NQKV, 0, blockIdx.y * 128, blockIdx.x * 128);
}

// out_gemm + fused main-tile copy into out[:, 0:768]
__global__ __launch_bounds__(256) void out_gemm(const unsigned short* __restrict__ ctx,
                                                const unsigned short* __restrict__ w,
                                                const float* __restrict__ bias,
                                                const float* __restrict__ main_,
                                                float* __restrict__ out) {
    const int m0 = blockIdx.y * 128;
    const int n0 = blockIdx.x * 128;
    gemm_tile<false>(ctx, w, bias, out, 2 * D, D, m0, n0);
    const int tid = threadIdx.x;
#pragma unroll
    for (int it = 0; it < 16; it++) {
        const int idx = tid + it * 256;  // 128 rows x 32 float4
        const int r = idx >> 5, c4 = idx & 31;
        const float4 v = *(const float4*)(main_ + (size_t)(m0 + r) * D + n0 + c4 * 4);
        *(float4*)(out + (size_t)(m0 + r) * (2 * D) + n0 + c4 * 4) = v;
    }
}

// ---- attention over merged QKV buffer --------------------------------------
// Q row for line n = QKV[n + OVL][0:768]; K/V rows r = QKV[r][768/1536 + ...]
__global__ __launch_bounds__(256) void attn_kernel(const unsigned short* __restrict__ QKV,
                                                   unsigned short* __restrict__ ctx) {
    const int n0 = blockIdx.x * CH;
    const int h = blockIdx.y;
    const int tid = threadIdx.x;

    __shared__ __align__(16) unsigned short sQ[CH * 104];  // reused as output stage
    __shared__ __align__(16) unsigned short sK[128 * 104];
    __shared__ __align__(16) unsigned short sV[128 * 104];
    __shared__ float sS[CH][17];

    // Q: lines n0..n0+63 -> QKV rows n0+OVL.. ; 64 rows x 12 uint4
#pragma unroll
    for (int it = 0; it < 3; it++) {
        const int idx = tid + it * 256;
        const int row = idx / 12, c = idx % 12;
        *(uint4*)(sQ + row * 104 + c * 8) =
            *(const uint4*)(QKV + (size_t)(n0 + OVL + row) * NQKV + h * HD + c * 8);
    }
    // K,V: QKV rows n0..n0+127 (the exact window span), 128 x 12 uint4 each
#pragma unroll
    for (int it = 0; it < 6; it++) {
        const int idx = tid + it * 256;
        const int row = idx / 12, c = idx % 12;
        *(uint4*)(sK + row * 104 + c * 8) =
            *(const uint4*)(QKV + (size_t)(n0 + row) * NQKV + D + h * HD + c * 8);
        *(uint4*)(sV + row * 104 + c * 8) =
            *(const uint4*)(QKV + (size_t)(n0 + row) * NQKV + 2 * D + h * HD + c * 8);
    }
    __syncthreads();

    const int l = tid & 63;
    const int wg = tid >> 6;

    uint4 qreg[12];
#pragma unroll
    for (int c = 0; c < 12; c++) qreg[c] = *(const uint4*)(sQ + l * 104 + c * 8);
#pragma unroll
    for (int wi = 0; wi < 4; wi++) {
        const int w = wg * 4 + wi;
        const int lrow = l + 4 * w + (w >= 8 ? 4 : 0);
        float s = 0.f;
#pragma unroll
        for (int c = 0; c < 12; c++) {
            const uint4 kv = *(const uint4*)(sK + lrow * 104 + c * 8);
            s += bflo(qreg[c].x) * bflo(kv.x) + bfhi(qreg[c].x) * bfhi(kv.x);
            s += bflo(qreg[c].y) * bflo(kv.y) + bfhi(qreg[c].y) * bfhi(kv.y);
            s += bflo(qreg[c].z) * bflo(kv.z) + bfhi(qreg[c].z) * bfhi(kv.z);
            s += bflo(qreg[c].w) * bflo(kv.w) + bfhi(qreg[c].w) * bfhi(kv.w);
        }
        sS[l][w] = s;
    }
    __syncthreads();

    if (tid < CH) {
        float mx = -1e30f;
#pragma unroll
        for (int i = 0; i < NW; i++) mx = fmaxf(mx, sS[tid][i]);
        float e[NW], sum = 0.f;
#pragma unroll
        for (int i = 0; i < NW; i++) {
            e[i] = __expf(sS[tid][i] - mx);
            sum += e[i];
        }
        const float inv = 1.f / sum;
#pragma unroll
        for (int i = 0; i < NW; i++) sS[tid][i] = e[i] * inv;
    }
    __syncthreads();

    {
        float p[NW];
#pragma unroll
        for (int i = 0; i < NW; i++) p[i] = sS[l][i];
        float acc[24] = {};
#pragma unroll
        for (int i = 0; i < NW; i++) {
            const int lrow = l + 4 * i + (i >= 8 ? 4 : 0);
            const unsigned short* vp = sV + lrow * 104 + wg * 24;
            const float pw = p[i];
#pragma unroll
            for (int c = 0; c < 3; c++) {
                const uint4 vv = *(const uint4*)(vp + c * 8);
                acc[c * 8 + 0] += pw * bflo(vv.x);
                acc[c * 8 + 1] += pw * bfhi(vv.x);
                acc[c * 8 + 2] += pw * bflo(vv.y);
                acc[c * 8 + 3] += pw * bfhi(vv.y);
                acc[c * 8 + 4] += pw * bflo(vv.z);
                acc[c * 8 + 5] += pw * bfhi(vv.z);
                acc[c * 8 + 6] += pw * bflo(vv.w);
                acc[c * 8 + 7] += pw * bfhi(vv.w);
            }
        }
        __syncthreads();
        unsigned short* op = sQ + l * 104 + wg * 24;
#pragma unroll
        for (int c = 0; c < 12; c++) {
            *(unsigned int*)(op + c * 2) =
                (unsigned int)f2bf(acc[c * 2]) | ((unsigned int)f2bf(acc[c * 2 + 1]) << 16);
        }
    }
    __syncthreads();

#pragma unroll
    for (int it = 0; it < 12; it++) {
        const int idx = tid + it * 256;
        const int row = idx / 48, cu = idx % 48;
        const unsigned int v = *(const unsigned int*)(sQ + row * 104 + cu * 2);
        *(unsigned int*)(ctx + (size_t)(n0 + row) * D + h * HD + cu * 2) = v;
    }
}

extern "C" void kernel_launch(void* const* d_in, const int* in_sizes, int n_in,
                              void* d_out, int out_size, void* d_ws, size_t ws_size,
                              hipStream_t stream) {
    const float* main_ = (const float*)d_in[0];
    const float* begin_ = (const float*)d_in[1];
    const float* end_ = (const float*)d_in[2];
    const float* in_w = (const float*)d_in[3];
    const float* in_b = (const float*)d_in[4];
    const float* out_w = (const float*)d_in[5];
    const float* out_b = (const float*)d_in[6];
    float* out = (float*)d_out;

    // workspace layout (bf16 unless noted); total ~68.5 MB
    unsigned short* comb_bf = (unsigned short*)d_ws;        // MPAD*D
    unsigned short* w_bf = comb_bf + (size_t)MPAD * D;      // 4*D*D (in3 + out)
    unsigned short* QKVb = w_bf + (size_t)4 * D * D;        // MPAD*NQKV
    unsigned short* ctxb = QKVb + (size_t)MPAD * NQKV;      // NLINES*D
    float* bias_s = (float*)(ctxb + (size_t)NLINES * D);    // NQKV fp32

    convert_comb<<<MPAD * (D / 4) / 256, 256, 0, stream>>>(main_, begin_, end_, comb_bf);
    convert_w<<<4 * D * D / 1024, 256, 0, stream>>>(in_w, in_b, out_w, w_bf, bias_s);
    qkv_gemm<<<dim3(NQKV / 128, MPAD / 128), 256, 0, stream>>>(comb_bf, w_bf, bias_s, QKVb);
    attn_kernel<<<dim3(NLINES / CH, NH), 256, 0, stream>>>(QKVb, ctxb);
    out_gemm<<<dim3(D / 128, NLINES / 128), 256, 0, stream>>>(ctxb, w_bf + (size_t)3 * D * D,
                                                              out_b, main_, out);
}

// Round 5
// 176.054 us; speedup vs baseline: 1.1476x; 1.1476x over previous
//
#include <hip/hip_runtime.h>
#include <math.h>

#define D 768
#define NQKV 2304
#define NH 8
#define HD 96
#define NW 16
#define OVL 32
#define NLINES 8192
#define NCOMB 8256
#define MPAD 8320  // 65 * 128, zero-padded rows for guard-free GEMM
#define CH 64      // attention lines per block
#define SCALE_Q 0.1020620726159657f

typedef int i32x8 __attribute__((ext_vector_type(8)));
typedef float f32x4 __attribute__((ext_vector_type(4)));

__device__ __forceinline__ unsigned short f2bf(float f) {
    unsigned int u = __float_as_uint(f);
    u += 0x7FFF + ((u >> 16) & 1);  // RNE
    return (unsigned short)(u >> 16);
}
__device__ __forceinline__ float bflo(unsigned int u) { return __uint_as_float(u << 16); }
__device__ __forceinline__ float bfhi(unsigned int u) { return __uint_as_float(u & 0xFFFF0000u); }

__device__ __forceinline__ void stage16(const void* g, void* l) {
    __builtin_amdgcn_global_load_lds(
        (const __attribute__((address_space(1))) unsigned int*)g,
        (__attribute__((address_space(3))) unsigned int*)l, 16, 0, 0);
}

// pack 4 floats -> 4 e4m3 bytes in one dword
__device__ __forceinline__ unsigned int pk_fp8x4(float a, float b, float c, float d) {
    int u = __builtin_amdgcn_cvt_pk_fp8_f32(a, b, 0, false);
    u = __builtin_amdgcn_cvt_pk_fp8_f32(c, d, u, true);
    return (unsigned int)u;
}

// ---- fp32 -> fp8 converts --------------------------------------------------

// combined = [begin; main; end] zero-padded to MPAD rows, e4m3
__global__ __launch_bounds__(256) void convert_comb(const float* __restrict__ main_,
                                                    const float* __restrict__ begin_,
                                                    const float* __restrict__ end_,
                                                    unsigned int* __restrict__ dst) {
    const int i = blockIdx.x * 256 + threadIdx.x;  // MPAD*192 float4 groups
    const int row = i / 192;
    const int c4 = i % 192;
    float4 v = make_float4(0.f, 0.f, 0.f, 0.f);
    if (row < NCOMB) {
        const float* src = (row < OVL) ? begin_ + (size_t)row * D
                         : (row < OVL + NLINES) ? main_ + (size_t)(row - OVL) * D
                                                : end_ + (size_t)(row - OVL - NLINES) * D;
        v = *(const float4*)(src + c4 * 4);
    }
    dst[(size_t)row * 192 + c4] = pk_fp8x4(v.x, v.y, v.z, v.w);
}

// weights -> e4m3, pre-scaled by 16 (dequant 2^-4 via MX scale); Wq also * SCALE_Q.
// w_dst = [in_proj_w (3DD); out_proj_w (DD)] bytes. Also preps scaled in-proj bias.
__global__ __launch_bounds__(256) void convert_w(const float* __restrict__ in_w,
                                                 const float* __restrict__ in_b,
                                                 const float* __restrict__ out_w,
                                                 unsigned int* __restrict__ w_dst,
                                                 float* __restrict__ bias_s) {
    const int i = blockIdx.x * 256 + threadIdx.x;  // over 4*D*D/4 dwords
    const int f0 = i * 4;
    const bool is_out = f0 >= 3 * D * D;
    const float4 v = is_out ? *(const float4*)(out_w + (f0 - 3 * D * D))
                            : *(const float4*)(in_w + f0);
    const float s = 16.0f * ((f0 < D * D) ? SCALE_Q : 1.0f);
    w_dst[i] = pk_fp8x4(v.x * s, v.y * s, v.z * s, v.w * s);
    if (blockIdx.x == 0) {
        for (int b = threadIdx.x; b < NQKV; b += 256)
            bias_s[b] = in_b[b] * (b < D ? SCALE_Q : 1.0f);
    }
}

// ---- MX-fp8 128x128 GEMM main loop: acc = A @ B^T (K=768, BK=128) ----------
// A,B: e4m3, row stride 768 B. B pre-scaled x16, HW dequant 2^-4 (scaleB=123).
__device__ __forceinline__ void gemm_f8_loop(const unsigned char* __restrict__ A,
                                             const unsigned char* __restrict__ B,
                                             unsigned char* As, unsigned char* Bs,
                                             int m0, int n0, f32x4 (&acc)[4][4]) {
    const int tid = threadIdx.x;
    const int lane = tid & 63;
    const int wave = tid >> 6;
    const int wm = (wave & 1) * 64;
    const int wn = (wave >> 1) * 64;
    const int q = lane >> 4;
    const int l15 = lane & 15;

    for (int k0 = 0; k0 < D; k0 += 128) {
#pragma unroll
        for (int it = 0; it < 4; it++) {
            const int ch = tid + it * 256;  // 1024 16B chunks per 128x128B tile
            const int row = ch >> 3, c16 = (ch & 7) * 16;
            stage16(A + (size_t)(m0 + row) * D + k0 + c16, As + ch * 16);
            stage16(B + (size_t)(n0 + row) * D + k0 + c16, Bs + ch * 16);
        }
        __syncthreads();
        i32x8 af[4], bfr[4];
#pragma unroll
        for (int i = 0; i < 4; i++)
            af[i] = *(const i32x8*)(As + (wm + i * 16 + l15) * 128 + q * 32);
#pragma unroll
        for (int j = 0; j < 4; j++)
            bfr[j] = *(const i32x8*)(Bs + (wn + j * 16 + l15) * 128 + q * 32);
#pragma unroll
        for (int i = 0; i < 4; i++)
#pragma unroll
            for (int j = 0; j < 4; j++)
                acc[i][j] = __builtin_amdgcn_mfma_scale_f32_16x16x128_f8f6f4(
                    af[i], bfr[j], acc[i][j], /*fmtA*/ 0, /*fmtB*/ 0,
                    /*opselA*/ 0, /*scaleA=1.0*/ 127, /*opselB*/ 0, /*scaleB=2^-4*/ 123);
        __syncthreads();
    }
}

// Merged QKV GEMM, split dense outputs: x-tiles 0-5 -> Q, 6-11 -> K, 12-17 -> V
__global__ __launch_bounds__(256) void qkv_gemm(const unsigned char* __restrict__ comb,
                                                const unsigned char* __restrict__ w_f8,
                                                const float* __restrict__ bias_s,
                                                unsigned short* __restrict__ Qb,
                                                unsigned short* __restrict__ Kb,
                                                unsigned short* __restrict__ Vb) {
    __shared__ __align__(16) unsigned char As[128 * 128];
    __shared__ __align__(16) unsigned char Bs[128 * 128];
    const int bx = blockIdx.x;
    const int m0 = blockIdx.y * 128;
    f32x4 acc[4][4] = {};
    gemm_f8_loop(comb, w_f8, As, Bs, m0, bx * 128, acc);

    const int lane = threadIdx.x & 63;
    const int wave = threadIdx.x >> 6;
    const int wm = (wave & 1) * 64, wn = (wave >> 1) * 64;
    const int q = lane >> 4, l15 = lane & 15;
    unsigned short* Cb = (bx < 6) ? Qb : (bx < 12 ? Kb : Vb);
    const int nloc = (bx % 6) * 128;
#pragma unroll
    for (int i = 0; i < 4; i++)
#pragma unroll
        for (int j = 0; j < 4; j++)
#pragma unroll
            for (int r = 0; r < 4; r++) {
                const int row = m0 + wm + i * 16 + q * 4 + r;
                const int col = wn + j * 16 + l15;
                const float v = acc[i][j][r] + bias_s[bx * 128 + col];
                Cb[(size_t)row * D + nloc + col] = f2bf(v);
            }
}

// out = [main | ctx @ Wo^T + bias], fp32, row stride 1536
__global__ __launch_bounds__(256) void out_gemm(const unsigned char* __restrict__ ctx,
                                                const unsigned char* __restrict__ w,
                                                const float* __restrict__ bias,
                                                const float* __restrict__ main_,
                                                float* __restrict__ out) {
    __shared__ __align__(16) unsigned char As[128 * 128];
    __shared__ __align__(16) unsigned char Bs[128 * 128];
    const int m0 = blockIdx.y * 128;
    const int n0 = blockIdx.x * 128;
    f32x4 acc[4][4] = {};
    gemm_f8_loop(ctx, w, As, Bs, m0, n0, acc);

    const int tid = threadIdx.x;
    const int lane = tid & 63;
    const int wave = tid >> 6;
    const int wm = (wave & 1) * 64, wn = (wave >> 1) * 64;
    const int q = lane >> 4, l15 = lane & 15;
#pragma unroll
    for (int i = 0; i < 4; i++)
#pragma unroll
        for (int j = 0; j < 4; j++)
#pragma unroll
            for (int r = 0; r < 4; r++) {
                const int row = m0 + wm + i * 16 + q * 4 + r;
                const int col = n0 + wn + j * 16 + l15;
                out[(size_t)row * (2 * D) + D + col] = acc[i][j][r] + bias[col];
            }
    // fused main-tile copy into out[:, 0:768]
#pragma unroll
    for (int it = 0; it < 16; it++) {
        const int idx = tid + it * 256;  // 128 rows x 32 float4
        const int r = idx >> 5, c4 = idx & 31;
        const float4 v = *(const float4*)(main_ + (size_t)(m0 + r) * D + n0 + c4 * 4);
        *(float4*)(out + (size_t)(m0 + r) * (2 * D) + n0 + c4 * 4) = v;
    }
}

// ---- attention: 64 lines x 1 head per block; bf16 in, fp8 ctx out ----------
// Q is passed pre-offset by OVL rows (Q row for line n = Qb[n + OVL]).
__global__ __launch_bounds__(256) void attn_kernel(const unsigned short* __restrict__ Q,
                                                   const unsigned short* __restrict__ K,
                                                   const unsigned short* __restrict__ V,
                                                   unsigned char* __restrict__ ctx) {
    const int n0 = blockIdx.x * CH;
    const int h = blockIdx.y;
    const int tid = threadIdx.x;

    __shared__ __align__(16) unsigned short sQ[CH * 104];
    __shared__ __align__(16) unsigned short sK[128 * 104];
    __shared__ __align__(16) unsigned short sV[128 * 104];
    __shared__ float sS[CH][17];

#pragma unroll
    for (int it = 0; it < 3; it++) {
        const int idx = tid + it * 256;
        const int row = idx / 12, c = idx % 12;
        *(uint4*)(sQ + row * 104 + c * 8) =
            *(const uint4*)(Q + (size_t)(n0 + row) * D + h * HD + c * 8);
    }
#pragma unroll
    for (int it = 0; it < 6; it++) {
        const int idx = tid + it * 256;
        const int row = idx / 12, c = idx % 12;
        *(uint4*)(sK + row * 104 + c * 8) =
            *(const uint4*)(K + (size_t)(n0 + row) * D + h * HD + c * 8);
        *(uint4*)(sV + row * 104 + c * 8) =
            *(const uint4*)(V + (size_t)(n0 + row) * D + h * HD + c * 8);
    }
    __syncthreads();

    const int l = tid & 63;
    const int wg = tid >> 6;

    uint4 qreg[12];
#pragma unroll
    for (int c = 0; c < 12; c++) qreg[c] = *(const uint4*)(sQ + l * 104 + c * 8);
#pragma unroll
    for (int wi = 0; wi < 4; wi++) {
        const int w = wg * 4 + wi;
        const int lrow = l + 4 * w + (w >= 8 ? 4 : 0);
        float s = 0.f;
#pragma unroll
        for (int c = 0; c < 12; c++) {
            const uint4 kv = *(const uint4*)(sK + lrow * 104 + c * 8);
            s += bflo(qreg[c].x) * bflo(kv.x) + bfhi(qreg[c].x) * bfhi(kv.x);
            s += bflo(qreg[c].y) * bflo(kv.y) + bfhi(qreg[c].y) * bfhi(kv.y);
            s += bflo(qreg[c].z) * bflo(kv.z) + bfhi(qreg[c].z) * bfhi(kv.z);
            s += bflo(qreg[c].w) * bflo(kv.w) + bfhi(qreg[c].w) * bfhi(kv.w);
        }
        sS[l][w] = s;
    }
    __syncthreads();

    if (tid < CH) {
        float mx = -1e30f;
#pragma unroll
        for (int i = 0; i < NW; i++) mx = fmaxf(mx, sS[tid][i]);
        float e[NW], sum = 0.f;
#pragma unroll
        for (int i = 0; i < NW; i++) {
            e[i] = __expf(sS[tid][i] - mx);
            sum += e[i];
        }
        const float inv = 1.f / sum;
#pragma unroll
        for (int i = 0; i < NW; i++) sS[tid][i] = e[i] * inv;
    }
    __syncthreads();

    // ctx dims wg*24..wg*24+23 of line l; write e4m3 directly from registers
    float p[NW];
#pragma unroll
    for (int i = 0; i < NW; i++) p[i] = sS[l][i];
    float acc[24] = {};
#pragma unroll
    for (int i = 0; i < NW; i++) {
        const int lrow = l + 4 * i + (i >= 8 ? 4 : 0);
        const unsigned short* vp = sV + lrow * 104 + wg * 24;
        const float pw = p[i];
#pragma unroll
        for (int c = 0; c < 3; c++) {
            const uint4 vv = *(const uint4*)(vp + c * 8);
            acc[c * 8 + 0] += pw * bflo(vv.x);
            acc[c * 8 + 1] += pw * bfhi(vv.x);
            acc[c * 8 + 2] += pw * bflo(vv.y);
            acc[c * 8 + 3] += pw * bfhi(vv.y);
            acc[c * 8 + 4] += pw * bflo(vv.z);
            acc[c * 8 + 5] += pw * bfhi(vv.z);
            acc[c * 8 + 6] += pw * bflo(vv.w);
            acc[c * 8 + 7] += pw * bfhi(vv.w);
        }
    }
    unsigned char* op = ctx + (size_t)(n0 + l) * D + h * HD + wg * 24;
#pragma unroll
    for (int c = 0; c < 3; c++) {
        const unsigned int u0 = pk_fp8x4(acc[c * 8 + 0], acc[c * 8 + 1], acc[c * 8 + 2], acc[c * 8 + 3]);
        const unsigned int u1 = pk_fp8x4(acc[c * 8 + 4], acc[c * 8 + 5], acc[c * 8 + 6], acc[c * 8 + 7]);
        *(uint2*)(op + c * 8) = make_uint2(u0, u1);
    }
}

extern "C" void kernel_launch(void* const* d_in, const int* in_sizes, int n_in,
                              void* d_out, int out_size, void* d_ws, size_t ws_size,
                              hipStream_t stream) {
    const float* main_ = (const float*)d_in[0];
    const float* begin_ = (const float*)d_in[1];
    const float* end_ = (const float*)d_in[2];
    const float* in_w = (const float*)d_in[3];
    const float* in_b = (const float*)d_in[4];
    const float* out_w = (const float*)d_in[5];
    const float* out_b = (const float*)d_in[6];
    float* out = (float*)d_out;

    // workspace: fp8 A/W + bf16 QKV + fp8 ctx; ~53.4 MB total, all 16B-aligned
    unsigned char* comb_f8 = (unsigned char*)d_ws;                  // MPAD*D bytes
    unsigned char* w_f8 = comb_f8 + (size_t)MPAD * D;               // 4*D*D bytes
    unsigned short* Qb = (unsigned short*)(w_f8 + (size_t)4 * D * D);  // MPAD*D bf16
    unsigned short* Kb = Qb + (size_t)MPAD * D;                     // MPAD*D bf16
    unsigned short* Vb = Kb + (size_t)MPAD * D;                     // MPAD*D bf16
    unsigned char* ctx_f8 = (unsigned char*)(Vb + (size_t)MPAD * D);  // NLINES*D bytes
    float* bias_s = (float*)(ctx_f8 + (size_t)NLINES * D);          // NQKV fp32

    convert_comb<<<MPAD * 192 / 256, 256, 0, stream>>>(main_, begin_, end_,
                                                       (unsigned int*)comb_f8);
    convert_w<<<4 * D * D / 1024, 256, 0, stream>>>(in_w, in_b, out_w,
                                                    (unsigned int*)w_f8, bias_s);
    qkv_gemm<<<dim3(NQKV / 128, MPAD / 128), 256, 0, stream>>>(comb_f8, w_f8, bias_s,
                                                               Qb, Kb, Vb);
    attn_kernel<<<dim3(NLINES / CH, NH), 256, 0, stream>>>(Qb + (size_t)OVL * D, Kb, Vb,
                                                           ctx_f8);
    out_gemm<<<dim3(D / 128, NLINES / 128), 256, 0, stream>>>(ctx_f8, w_f8 + (size_t)3 * D * D,
                                                              out_b, main_, out);
}

// Round 6
// 164.683 us; speedup vs baseline: 1.2269x; 1.0690x over previous
//
#include <hip/hip_runtime.h>
#include <math.h>

#define D 768
#define NQKV 2304
#define NH 8
#define HD 96
#define NW 16
#define OVL 32
#define NLINES 8192
#define NCOMB 8256
#define MPAD 8320  // 65 * 128 zero-padded rows
#define CH 64
#define SCALE_Q 0.1020620726159657f
#define COMB_BLOCKS 6240  // MPAD*192/256

typedef int i32x8 __attribute__((ext_vector_type(8)));
typedef float f32x4 __attribute__((ext_vector_type(4)));
typedef float f32x2 __attribute__((ext_vector_type(2)));

__device__ __forceinline__ unsigned int pk_fp8x4(float a, float b, float c, float d) {
    int u = __builtin_amdgcn_cvt_pk_fp8_f32(a, b, 0, false);
    u = __builtin_amdgcn_cvt_pk_fp8_f32(c, d, u, true);
    return (unsigned int)u;
}
__device__ __forceinline__ unsigned char f2fp8(float v) {
    return (unsigned char)(__builtin_amdgcn_cvt_pk_fp8_f32(v, v, 0, false) & 0xFF);
}
template <bool HI>
__device__ __forceinline__ f32x2 upk(unsigned int u) {
    return __builtin_amdgcn_cvt_pk_f32_fp8((int)u, HI);
}
__device__ __forceinline__ float dot4f8(unsigned int a, unsigned int b) {
    const f32x2 al = upk<false>(a), ah = upk<true>(a);
    const f32x2 bl = upk<false>(b), bh = upk<true>(b);
    return al.x * bl.x + al.y * bl.y + ah.x * bh.x + ah.y * bh.y;
}

__device__ __forceinline__ void stage16(const void* g, void* l) {
    __builtin_amdgcn_global_load_lds(
        (const __attribute__((address_space(1))) unsigned int*)g,
        (__attribute__((address_space(3))) unsigned int*)l, 16, 0, 0);
}

// Swizzled staging: LDS chunk ch (16B) of a [rows x 128B] tile. Stored quad
// s=(ch>>1)&3 holds original quad o=(s-row)&3, so fragment reads at
// row*128 + ((q+row)&3)*32 are conflict-free while LDS dests stay linear
// (global_load_lds requires wave-uniform base + lane*16).
__device__ __forceinline__ void stage_sw(const unsigned char* gbase, unsigned char* lds, int ch) {
    const int row = ch >> 3;
    const int half = ch & 1;
    const int o = (((ch >> 1) & 3) - row) & 3;
    stage16(gbase + (size_t)row * D + o * 32 + half * 16, lds + ch * 16);
}

// ---- fused fp32 -> fp8 converts (comb + weights + bias) --------------------
__global__ __launch_bounds__(256) void convert_all(const float* __restrict__ main_,
                                                   const float* __restrict__ begin_,
                                                   const float* __restrict__ end_,
                                                   const float* __restrict__ in_w,
                                                   const float* __restrict__ in_b,
                                                   const float* __restrict__ out_w,
                                                   unsigned int* __restrict__ comb_dst,
                                                   unsigned int* __restrict__ w_dst,
                                                   float* __restrict__ bias_s) {
    const int bid = blockIdx.x;
    if (bid < COMB_BLOCKS) {
        const int i = bid * 256 + threadIdx.x;  // dword index over MPAD*192
        const int row = i / 192, c4 = i % 192;
        float4 v = make_float4(0.f, 0.f, 0.f, 0.f);
        if (row < NCOMB) {
            const float* src = (row < OVL) ? begin_ + (size_t)row * D
                             : (row < OVL + NLINES) ? main_ + (size_t)(row - OVL) * D
                                                    : end_ + (size_t)(row - OVL - NLINES) * D;
            v = *(const float4*)(src + c4 * 4);
        }
        comb_dst[(size_t)row * 192 + c4] = pk_fp8x4(v.x, v.y, v.z, v.w);
    } else {
        const int j = (bid - COMB_BLOCKS) * 256 + threadIdx.x;  // dwords over 4*D*D
        const int f0 = j * 4;
        const bool is_out = f0 >= 3 * D * D;
        const float4 v = is_out ? *(const float4*)(out_w + (f0 - 3 * D * D))
                                : *(const float4*)(in_w + f0);
        const float s = 16.0f * ((f0 < D * D) ? SCALE_Q : 1.0f);
        w_dst[j] = pk_fp8x4(v.x * s, v.y * s, v.z * s, v.w * s);
        if (bid == COMB_BLOCKS) {
            for (int b = threadIdx.x; b < NQKV; b += 256)
                bias_s[b] = in_b[b] * (b < D ? SCALE_Q : 1.0f);
        }
    }
}

// ---- merged QKV GEMM (MX-fp8, swizzled LDS), fp8 outputs -------------------
__global__ __launch_bounds__(256) void qkv_gemm(const unsigned char* __restrict__ comb,
                                                const unsigned char* __restrict__ w_f8,
                                                const float* __restrict__ bias_s,
                                                unsigned char* __restrict__ Qb,
                                                unsigned char* __restrict__ Kb,
                                                unsigned char* __restrict__ Vb) {
    __shared__ __align__(16) unsigned char As[128 * 128];
    __shared__ __align__(16) unsigned char Bs[128 * 128];
    const int bx = blockIdx.x;
    const int m0 = blockIdx.y * 128;
    const int n0 = bx * 128;
    const int tid = threadIdx.x;
    const int lane = tid & 63;
    const int wave = tid >> 6;
    const int wm = (wave & 1) * 64, wn = (wave >> 1) * 64;
    const int q = lane >> 4, l15 = lane & 15;
    const int swq = (q + l15) & 3;  // (q+row)&3 with row ≡ l15 (mod 4)

    f32x4 acc[4][4] = {};
    for (int k0 = 0; k0 < D; k0 += 128) {
#pragma unroll
        for (int it = 0; it < 4; it++) {
            const int ch = tid + it * 256;
            stage_sw(comb + (size_t)m0 * D + k0, As, ch);
            stage_sw(w_f8 + (size_t)n0 * D + k0, Bs, ch);
        }
        __syncthreads();
        i32x8 af[4], bfr[4];
#pragma unroll
        for (int i = 0; i < 4; i++)
            af[i] = *(const i32x8*)(As + (wm + i * 16 + l15) * 128 + swq * 32);
#pragma unroll
        for (int j = 0; j < 4; j++)
            bfr[j] = *(const i32x8*)(Bs + (wn + j * 16 + l15) * 128 + swq * 32);
#pragma unroll
        for (int i = 0; i < 4; i++)
#pragma unroll
            for (int j = 0; j < 4; j++)
                acc[i][j] = __builtin_amdgcn_mfma_scale_f32_16x16x128_f8f6f4(
                    af[i], bfr[j], acc[i][j], 0, 0, 0, 127, 0, 123);
        __syncthreads();
    }

    unsigned char* Cb = (bx < 6) ? Qb : (bx < 12 ? Kb : Vb);
    const int nloc = (bx % 6) * 128;
#pragma unroll
    for (int i = 0; i < 4; i++)
#pragma unroll
        for (int j = 0; j < 4; j++)
#pragma unroll
            for (int r = 0; r < 4; r++) {
                const int row = m0 + wm + i * 16 + q * 4 + r;
                const int col = wn + j * 16 + l15;
                Cb[(size_t)row * D + nloc + col] = f2fp8(acc[i][j][r] + bias_s[bx * 128 + col]);
            }
}

// ---- out proj (MX-fp8, 64x128 tiles for occupancy) + fused main copy -------
__global__ __launch_bounds__(256) void out_gemm(const unsigned char* __restrict__ ctx,
                                                const unsigned char* __restrict__ w,
                                                const float* __restrict__ bias,
                                                const float* __restrict__ main_,
                                                float* __restrict__ out) {
    __shared__ __align__(16) unsigned char As[64 * 128];
    __shared__ __align__(16) unsigned char Bs[128 * 128];
    const int m0 = blockIdx.y * 64;
    const int n0 = blockIdx.x * 128;
    const int tid = threadIdx.x;
    const int lane = tid & 63;
    const int wave = tid >> 6;
    const int wn = wave * 32;
    const int q = lane >> 4, l15 = lane & 15;
    const int swq = (q + l15) & 3;

    f32x4 acc[4][2] = {};
    for (int k0 = 0; k0 < D; k0 += 128) {
#pragma unroll
        for (int it = 0; it < 2; it++)
            stage_sw(ctx + (size_t)m0 * D + k0, As, tid + it * 256);
#pragma unroll
        for (int it = 0; it < 4; it++)
            stage_sw(w + (size_t)n0 * D + k0, Bs, tid + it * 256);
        __syncthreads();
        i32x8 af[4], bfr[2];
#pragma unroll
        for (int i = 0; i < 4; i++)
            af[i] = *(const i32x8*)(As + (i * 16 + l15) * 128 + swq * 32);
#pragma unroll
        for (int j = 0; j < 2; j++)
            bfr[j] = *(const i32x8*)(Bs + (wn + j * 16 + l15) * 128 + swq * 32);
#pragma unroll
        for (int i = 0; i < 4; i++)
#pragma unroll
            for (int j = 0; j < 2; j++)
                acc[i][j] = __builtin_amdgcn_mfma_scale_f32_16x16x128_f8f6f4(
                    af[i], bfr[j], acc[i][j], 0, 0, 0, 127, 0, 123);
        __syncthreads();
    }

#pragma unroll
    for (int i = 0; i < 4; i++)
#pragma unroll
        for (int j = 0; j < 2; j++)
#pragma unroll
            for (int r = 0; r < 4; r++) {
                const int row = m0 + i * 16 + q * 4 + r;
                const int col = n0 + wn + j * 16 + l15;
                out[(size_t)row * (2 * D) + D + col] = acc[i][j][r] + bias[col];
            }
    // fused main-tile copy (64 rows x 32 float4)
#pragma unroll
    for (int it = 0; it < 8; it++) {
        const int idx = tid + it * 256;
        const int r = idx >> 5, c4 = idx & 31;
        const float4 v = *(const float4*)(main_ + (size_t)(m0 + r) * D + n0 + c4 * 4);
        *(float4*)(out + (size_t)(m0 + r) * (2 * D) + n0 + c4 * 4) = v;
    }
}

// ---- attention: fp8 Q/K/V, 64 lines x 1 head per block ---------------------
// Q pre-offset by OVL rows. LDS ~35 KB -> 4 blocks/CU.
__global__ __launch_bounds__(256) void attn_kernel(const unsigned char* __restrict__ Q,
                                                   const unsigned char* __restrict__ K,
                                                   const unsigned char* __restrict__ V,
                                                   unsigned char* __restrict__ ctx) {
    const int n0 = blockIdx.x * CH;
    const int h = blockIdx.y;
    const int tid = threadIdx.x;

    __shared__ __align__(16) unsigned char sQ[CH * 96];
    __shared__ __align__(16) unsigned char sK[128 * 96];
    __shared__ __align__(16) unsigned char sV[128 * 96];
    __shared__ float sS[CH][17];

    for (int idx = tid; idx < 384; idx += 256) {  // 64 rows x 6 chunks
        const int row = idx / 6, c = idx % 6;
        *(uint4*)(sQ + row * 96 + c * 16) =
            *(const uint4*)(Q + (size_t)(n0 + row) * D + h * HD + c * 16);
    }
#pragma unroll
    for (int it = 0; it < 3; it++) {  // 128 rows x 6 chunks each
        const int idx = tid + it * 256;
        const int row = idx / 6, c = idx % 6;
        *(uint4*)(sK + row * 96 + c * 16) =
            *(const uint4*)(K + (size_t)(n0 + row) * D + h * HD + c * 16);
        *(uint4*)(sV + row * 96 + c * 16) =
            *(const uint4*)(V + (size_t)(n0 + row) * D + h * HD + c * 16);
    }
    __syncthreads();

    const int l = tid & 63;
    const int wg = tid >> 6;

#pragma unroll
    for (int wi = 0; wi < 4; wi++) {
        const int w = wg * 4 + wi;
        const int lrow = l + 4 * w + (w >= 8 ? 4 : 0);
        float s = 0.f;
#pragma unroll
        for (int c = 0; c < 6; c++) {
            const uint4 qa = *(const uint4*)(sQ + l * 96 + c * 16);
            const uint4 ka = *(const uint4*)(sK + lrow * 96 + c * 16);
            s += dot4f8(qa.x, ka.x) + dot4f8(qa.y, ka.y) +
                 dot4f8(qa.z, ka.z) + dot4f8(qa.w, ka.w);
        }
        sS[l][w] = s;
    }
    __syncthreads();

    if (tid < CH) {
        float mx = -1e30f;
#pragma unroll
        for (int i = 0; i < NW; i++) mx = fmaxf(mx, sS[tid][i]);
        float e[NW], sum = 0.f;
#pragma unroll
        for (int i = 0; i < NW; i++) {
            e[i] = __expf(sS[tid][i] - mx);
            sum += e[i];
        }
        const float inv = 1.f / sum;
#pragma unroll
        for (int i = 0; i < NW; i++) sS[tid][i] = e[i] * inv;
    }
    __syncthreads();

    float p[NW];
#pragma unroll
    for (int i = 0; i < NW; i++) p[i] = sS[l][i];
    float acc[24] = {};
#pragma unroll
    for (int i = 0; i < NW; i++) {
        const int lrow = l + 4 * i + (i >= 8 ? 4 : 0);
        const unsigned char* vp = sV + lrow * 96 + wg * 24;
        const float pw = p[i];
#pragma unroll
        for (int c = 0; c < 3; c++) {
            const uint2 vv = *(const uint2*)(vp + c * 8);
            const f32x2 a0 = upk<false>(vv.x), a1 = upk<true>(vv.x);
            const f32x2 a2 = upk<false>(vv.y), a3 = upk<true>(vv.y);
            acc[c * 8 + 0] += pw * a0.x;
            acc[c * 8 + 1] += pw * a0.y;
            acc[c * 8 + 2] += pw * a1.x;
            acc[c * 8 + 3] += pw * a1.y;
            acc[c * 8 + 4] += pw * a2.x;
            acc[c * 8 + 5] += pw * a2.y;
            acc[c * 8 + 6] += pw * a3.x;
            acc[c * 8 + 7] += pw * a3.y;
        }
    }
    unsigned char* op = ctx + (size_t)(n0 + l) * D + h * HD + wg * 24;
#pragma unroll
    for (int c = 0; c < 3; c++) {
        const unsigned int u0 =
            pk_fp8x4(acc[c * 8 + 0], acc[c * 8 + 1], acc[c * 8 + 2], acc[c * 8 + 3]);
        const unsigned int u1 =
            pk_fp8x4(acc[c * 8 + 4], acc[c * 8 + 5], acc[c * 8 + 6], acc[c * 8 + 7]);
        *(uint2*)(op + c * 8) = make_uint2(u0, u1);
    }
}

extern "C" void kernel_launch(void* const* d_in, const int* in_sizes, int n_in,
                              void* d_out, int out_size, void* d_ws, size_t ws_size,
                              hipStream_t stream) {
    const float* main_ = (const float*)d_in[0];
    const float* begin_ = (const float*)d_in[1];
    const float* end_ = (const float*)d_in[2];
    const float* in_w = (const float*)d_in[3];
    const float* in_b = (const float*)d_in[4];
    const float* out_w = (const float*)d_in[5];
    const float* out_b = (const float*)d_in[6];
    float* out = (float*)d_out;

    // workspace (~34 MB), all 16B-aligned
    unsigned char* comb_f8 = (unsigned char*)d_ws;             // MPAD*D
    unsigned char* w_f8 = comb_f8 + (size_t)MPAD * D;          // 4*D*D
    unsigned char* Qb = w_f8 + (size_t)4 * D * D;              // MPAD*D
    unsigned char* Kb = Qb + (size_t)MPAD * D;                 // MPAD*D
    unsigned char* Vb = Kb + (size_t)MPAD * D;                 // MPAD*D
    unsigned char* ctx_f8 = Vb + (size_t)MPAD * D;             // NLINES*D
    float* bias_s = (float*)(ctx_f8 + (size_t)NLINES * D);     // NQKV fp32

    convert_all<<<COMB_BLOCKS + 4 * D * D / 1024, 256, 0, stream>>>(
        main_, begin_, end_, in_w, in_b, out_w, (unsigned int*)comb_f8,
        (unsigned int*)w_f8, bias_s);
    qkv_gemm<<<dim3(NQKV / 128, MPAD / 128), 256, 0, stream>>>(comb_f8, w_f8, bias_s,
                                                               Qb, Kb, Vb);
    attn_kernel<<<dim3(NLINES / CH, NH), 256, 0, stream>>>(Qb + (size_t)OVL * D, Kb, Vb,
                                                           ctx_f8);
    out_gemm<<<dim3(D / 128, NLINES / 64), 256, 0, stream>>>(ctx_f8, w_f8 + (size_t)3 * D * D,
                                                             out_b, main_, out);
}